// Round 3
// baseline (245.545 us; speedup 1.0000x reference)
//
#include <hip/hip_runtime.h>
#include <hip/hip_bf16.h>

// LinearAttention: B=8, C=512, L=4096, HEADS=8, dim_head=64, hidden=512
// R8: gemm1 fused with softmax-context: block = (n-slice, head, batch) computes
//     paired {k,v} 128x128 tile, then in-block P=exp(k), row-sums, P@V^T partial
//     -> atomicAdd into ctx[b][h][64][64] (1MB) + S[b][h][64]. k,v never hit HBM
//     (-64MB write, -64MB read, -1 dispatch). w2 folds 1/S and register-blocks.
// Pipeline: prep_all(+zero ctx,S); gemm_kv; w2; W3=w2@Wq(gemm_bt); out=gemm_p(W3,xt).

typedef __bf16 bf16x8 __attribute__((ext_vector_type(8)));
typedef __bf16 bf16x4 __attribute__((ext_vector_type(4)));
typedef float  f32x4  __attribute__((ext_vector_type(4)));

#define B_  8
#define L_  4096
#define C_  512

#define GLD_LDS16(g, l)                                             \
    __builtin_amdgcn_global_load_lds(                               \
        (const __attribute__((address_space(1))) void*)(g),         \
        (__attribute__((address_space(3))) void*)(l), 16, 0, 0)

#define FENCE asm volatile("" ::: "memory")
#define BAR   do { FENCE; __builtin_amdgcn_s_barrier(); FENCE; } while (0)
#define DRAIN_LGKM asm volatile("s_waitcnt lgkmcnt(0)" ::: "memory")
#define WAIT_VM(N) asm volatile("s_waitcnt vmcnt(" #N ")" ::: "memory")

// ---------------- prep_all: x-transpose+cvt | wkv cvt | WqT | zero ctx+S ----------------
__global__ __launch_bounds__(256) void prep_all(const float* __restrict__ x,
                                                __hip_bfloat16* __restrict__ xt,
                                                const float* __restrict__ wqkv_f,
                                                __hip_bfloat16* __restrict__ wkv_b,
                                                __hip_bfloat16* __restrict__ wqT,
                                                float* __restrict__ zero_base) {
    __shared__ float tile[64 * 132];
    int blk = blockIdx.x;
    int t = threadIdx.x;
    if (blk < 2048) {
        // transpose fp32 x[b][C][L] -> bf16 xt[b][L][C]; 64c x 128l tile
        int b = blk >> 8, rem = blk & 255;
        int l0 = (rem & 31) * 128, c0 = (rem >> 5) * 64;
        const float* xp = x + ((size_t)b * C_ + c0) * L_ + l0;
#pragma unroll
        for (int p = 0; p < 8; p++) {
            int i = p * 8 + (t >> 5);
            int j = (t & 31) * 4;
            float4 vv = *(const float4*)(xp + (size_t)i * L_ + j);
            *(float4*)&tile[i * 132 + j] = vv;
        }
        __syncthreads();
        unsigned short* xo = (unsigned short*)xt + ((size_t)b * L_ + l0) * C_ + c0;
#pragma unroll
        for (int qq = 0; qq < 8; qq++) {
            int l = qq * 16 + (t >> 4);
            int cg = (t & 15) * 4;
            bf16x4 ov;
#pragma unroll
            for (int k = 0; k < 4; k++) ov[k] = (__bf16)tile[(cg + k) * 132 + l];
            *(bf16x4*)(xo + (size_t)l * C_ + cg) = ov;
        }
    } else if (blk < 4096) {
        int i = (blk - 2048) * 256 + t;  // 1024*512 elements (w_qkv rows 512..1535)
        wkv_b[i] = __float2bfloat16(wqkv_f[512 * 512 + i]);
    } else if (blk < 4352) {
        // wqT[c][c'] = w_qkv[c'][c] (q-part rows 0..511), bf16
        int tb = blk - 4096;
        int r0 = (tb >> 4) * 32, c0 = (tb & 15) * 32;
        int tx = t & 31, ty = t >> 5;
        for (int r = 0; r < 32; r += 8)
            tile[(ty + r) * 33 + tx] = wqkv_f[(size_t)(r0 + ty + r) * 512 + c0 + tx];
        __syncthreads();
        for (int r = 0; r < 32; r += 8)
            wqT[(size_t)(c0 + ty + r) * 512 + r0 + tx] = __float2bfloat16(tile[tx * 33 + ty + r]);
    } else {
        // zero ctx (8*8*64*64) + S (8*8*64) = 266240 contiguous floats
        int i = (blk - 4352) * 256 + t;
        zero_base[i] = 0.f;
    }
}

// ---------------- fused kv-GEMM + softmax-context ----------------
// Block (x=n-tile, y=head h, z=batch b): A-tile rows = {k[h*64..+63], v[h*64..+63]}
// (wkvb rows h*64+lr, lr<64; 448+h*64+lr, lr>=64), B-tile = xt n-slice 128 rows.
// Main loop: identical 2-phase counted-vmcnt pipeline (R7). Tail: P=exp(k) (wv0/1),
// V (wv2/3) stored bf16 to dead sA/sB as 256B rows, group g of row r at g^(r&15);
// row-sums S via shfl+atomicAdd; then P(64x128)@V^T(128x64) in 16 MFMA/wave,
// atomicAdd into ctx[b][h][d][e].
__global__ __launch_bounds__(256, 2) void gemm_kv(
    const __hip_bfloat16* __restrict__ A, const __hip_bfloat16* __restrict__ Bt,
    float* __restrict__ ctx, float* __restrict__ Ssum) {
    __shared__ alignas(16) unsigned short sA[2][128 * 64];  // 32 KiB
    __shared__ alignas(16) unsigned short sB[2][128 * 64];  // 32 KiB

    const int K = C_;
    int b = blockIdx.z, h = blockIdx.y;
    int n0 = blockIdx.x * 128;
    const __hip_bfloat16* Bb = Bt + (size_t)b * L_ * C_;

    int t = threadIdx.x;
    int lane = t & 63, wv = t >> 6;
    int l16 = lane & 15, q4 = lane >> 4;
    int wr = (wv >> 1) * 64, wc = (wv & 1) * 64;

    int srow = lane >> 3;
    int swz  = ((lane & 7) ^ srow) * 8;

    const __hip_bfloat16* gA[4];
    const __hip_bfloat16* gB[4];
    unsigned ldoff[4];
#pragma unroll
    for (int c = 0; c < 4; c++) {
        int r = c * 32 + wv * 8;
        int lr = r + srow;                             // local row 0..127
        int grow = h * 64 + lr + (lr >= 64 ? 448 : 0); // k rows / v rows of head h
        gA[c] = A + (size_t)grow * K + swz;
        gB[c] = Bb + (size_t)(n0 + lr) * K + swz;
        ldoff[c] = (unsigned)r * 64;
    }

    int gsel0 = (q4 ^ (l16 & 7)) * 8;
    int gsel1 = gsel0 ^ 32;
    unsigned rA = (unsigned)(wr + l16) * 64;
    unsigned rB = (unsigned)(wc + l16) * 64;
    const int NKT = K >> 6;  // 8

    f32x4 acc[4][4] = {};
    bf16x8 aF[4][2], bF[4][2];

    // prologue: tile0 A+B, tile1 A; leave tile1 A (4) in flight
#pragma unroll
    for (int c = 0; c < 4; c++) GLD_LDS16(gA[c], &sA[0][ldoff[c]]);
#pragma unroll
    for (int c = 0; c < 4; c++) GLD_LDS16(gB[c], &sB[0][ldoff[c]]);
#pragma unroll
    for (int c = 0; c < 4; c++) GLD_LDS16(gA[c] + 64, &sA[1][ldoff[c]]);
    WAIT_VM(4);
    BAR;

#pragma unroll 1
    for (int kt = 0; kt < NKT; ++kt) {
        int cur = kt & 1, nbuf = cur ^ 1;
        const unsigned short* As_b = sA[cur];
        const unsigned short* Bs_b = sB[cur];
        bool st1 = (kt + 1) < NKT;
        bool st2 = (kt + 2) < NKT;

        // ---- phase 0: acc[0-3][0-1]; stage B(kt+1) -> other buf
#pragma unroll
        for (int i = 0; i < 4; i++) {
            aF[i][0] = *(const bf16x8*)&As_b[rA + i * 1024 + gsel0];
            aF[i][1] = *(const bf16x8*)&As_b[rA + i * 1024 + gsel1];
        }
#pragma unroll
        for (int j = 0; j < 2; j++) {
            bF[j][0] = *(const bf16x8*)&Bs_b[rB + j * 1024 + gsel0];
            bF[j][1] = *(const bf16x8*)&Bs_b[rB + j * 1024 + gsel1];
        }
        if (st1) {
            int ko = (kt + 1) << 6;
#pragma unroll
            for (int c = 0; c < 4; c++) GLD_LDS16(gB[c] + ko, &sB[nbuf][ldoff[c]]);
        }
        BAR;
        __builtin_amdgcn_s_setprio(1);
#pragma unroll
        for (int ks = 0; ks < 2; ks++)
#pragma unroll
            for (int i = 0; i < 4; i++)
#pragma unroll
                for (int j = 0; j < 2; j++)
                    acc[i][j] = __builtin_amdgcn_mfma_f32_16x16x32_bf16(aF[i][ks], bF[j][ks], acc[i][j], 0, 0, 0);
        __builtin_amdgcn_s_setprio(0);
        DRAIN_LGKM;
        BAR;

        // ---- phase 1: acc[0-3][2-3]; stage A(kt+2) into SAME buffer
#pragma unroll
        for (int j = 2; j < 4; j++) {
            bF[j][0] = *(const bf16x8*)&Bs_b[rB + j * 1024 + gsel0];
            bF[j][1] = *(const bf16x8*)&Bs_b[rB + j * 1024 + gsel1];
        }
        if (st2) {
            int ko = (kt + 2) << 6;
#pragma unroll
            for (int c = 0; c < 4; c++) GLD_LDS16(gA[c] + ko, &sA[cur][ldoff[c]]);
        }
        BAR;
        __builtin_amdgcn_s_setprio(1);
#pragma unroll
        for (int ks = 0; ks < 2; ks++)
#pragma unroll
            for (int i = 0; i < 4; i++)
#pragma unroll
                for (int j = 0; j < 2; j++)
                    acc[i][2 + j] = __builtin_amdgcn_mfma_f32_16x16x32_bf16(aF[i][ks], bF[2 + j][ks], acc[i][2 + j], 0, 0, 0);
        __builtin_amdgcn_s_setprio(0);
        DRAIN_LGKM;
        if (st2) { WAIT_VM(4); } else { WAIT_VM(0); }
        BAR;
    }
    // final BAR above: all staging + ds_reads complete; sA/sB reusable.

    // ---- fused tail: P = exp(k) -> sA, V -> sB (bf16, 256B rows, group g^(row&15))
    __bf16* Pb = (__bf16*)sA;
    __bf16* Vb = (__bf16*)sB;
    float* ctxg = ctx  + ((size_t)b * 8 + h) * 4096;
    float* Sg   = Ssum + ((size_t)b * 8 + h) * 64;

    if (wv < 2) {
        // k-half: exp, store P, row-sums
#pragma unroll
        for (int i = 0; i < 4; i++)
#pragma unroll
            for (int r = 0; r < 4; r++) {
                int d = i * 16 + q4 * 4 + r;
                float rs = 0.f;
#pragma unroll
                for (int j = 0; j < 4; j++) {
                    int n = wc + j * 16 + l16;
                    float pv = __expf(acc[i][j][r]);
                    rs += pv;
                    Pb[d * 128 + (((n >> 3) ^ (d & 15)) * 8) + (n & 7)] = (__bf16)pv;
                }
                rs += __shfl_xor(rs, 1, 64);
                rs += __shfl_xor(rs, 2, 64);
                rs += __shfl_xor(rs, 4, 64);
                rs += __shfl_xor(rs, 8, 64);
                if (l16 == 0) atomicAdd(&Sg[d], rs);
            }
    } else {
        // v-half: store V
#pragma unroll
        for (int i = 0; i < 4; i++)
#pragma unroll
            for (int j = 0; j < 4; j++)
#pragma unroll
                for (int r = 0; r < 4; r++) {
                    int e = i * 16 + q4 * 4 + r;
                    int n = wc + j * 16 + l16;
                    Vb[e * 128 + (((n >> 3) ^ (e & 15)) * 8) + (n & 7)] = (__bf16)acc[i][j][r];
                }
    }
    DRAIN_LGKM;
    BAR;

    // ---- ctx partial: Cp[d][e] = sum_{n<128} P[d][n] V[e][n]; wave -> e in [wv*16,+16)
    f32x4 acc2[4] = {};
#pragma unroll
    for (int kk = 0; kk < 4; kk++) {
        int gg = kk * 4 + q4;
        bf16x8 bf2 = *(const bf16x8*)&Vb[(wv * 16 + l16) * 128 + ((gg ^ l16) * 8)];
#pragma unroll
        for (int i2 = 0; i2 < 4; i2++) {
            bf16x8 af2 = *(const bf16x8*)&Pb[(i2 * 16 + l16) * 128 + ((gg ^ l16) * 8)];
            acc2[i2] = __builtin_amdgcn_mfma_f32_16x16x32_bf16(af2, bf2, acc2[i2], 0, 0, 0);
        }
    }
#pragma unroll
    for (int i2 = 0; i2 < 4; i2++)
#pragma unroll
        for (int r = 0; r < 4; r++) {
            int d = i2 * 16 + q4 * 4 + r;
            int e = wv * 16 + l16;
            atomicAdd(&ctxg[d * 64 + e], acc2[i2][r]);
        }
}

// ---------------- pipelined 128^2 GEMM (out = W3 @ x + bias), fp32 out ----------------
__global__ __launch_bounds__(256, 2) void gemm_p(
    const __hip_bfloat16* __restrict__ A, const __hip_bfloat16* __restrict__ Bt,
    size_t strideA, size_t strideB, int M, int N, int K,
    float* __restrict__ outb, const float* __restrict__ bias) {
    __shared__ alignas(16) unsigned short sA[2][128 * 64];
    __shared__ alignas(16) unsigned short sB[2][128 * 64];

    int b = blockIdx.z;
    int m0 = blockIdx.y * 128, n0 = blockIdx.x * 128;
    const __hip_bfloat16* Ab = A + strideA * (size_t)b;
    const __hip_bfloat16* Bb = Bt + strideB * (size_t)b;

    int t = threadIdx.x;
    int lane = t & 63, wv = t >> 6;
    int l16 = lane & 15, q4 = lane >> 4;
    int wr = (wv >> 1) * 64, wc = (wv & 1) * 64;

    int srow = lane >> 3;
    int swz  = ((lane & 7) ^ srow) * 8;

    const __hip_bfloat16* gA[4];
    const __hip_bfloat16* gB[4];
    unsigned ldoff[4];
#pragma unroll
    for (int c = 0; c < 4; c++) {
        int r = c * 32 + wv * 8;
        gA[c] = Ab + (size_t)(m0 + r + srow) * K + swz;
        gB[c] = Bb + (size_t)(n0 + r + srow) * K + swz;
        ldoff[c] = (unsigned)r * 64;
    }

    int gsel0 = (q4 ^ (l16 & 7)) * 8;
    int gsel1 = gsel0 ^ 32;
    unsigned rA = (unsigned)(wr + l16) * 64;
    unsigned rB = (unsigned)(wc + l16) * 64;
    int NKT = K >> 6;

    f32x4 acc[4][4] = {};
    bf16x8 aF[4][2], bF[4][2];

#pragma unroll
    for (int c = 0; c < 4; c++) GLD_LDS16(gA[c], &sA[0][ldoff[c]]);
#pragma unroll
    for (int c = 0; c < 4; c++) GLD_LDS16(gB[c], &sB[0][ldoff[c]]);
    if (NKT > 1) {
#pragma unroll
        for (int c = 0; c < 4; c++) GLD_LDS16(gA[c] + 64, &sA[1][ldoff[c]]);
        WAIT_VM(4);
    } else {
        WAIT_VM(0);
    }
    BAR;

#pragma unroll 1
    for (int kt = 0; kt < NKT; ++kt) {
        int cur = kt & 1, nbuf = cur ^ 1;
        const unsigned short* As_b = sA[cur];
        const unsigned short* Bs_b = sB[cur];
        bool st1 = (kt + 1) < NKT;
        bool st2 = (kt + 2) < NKT;

#pragma unroll
        for (int i = 0; i < 4; i++) {
            aF[i][0] = *(const bf16x8*)&As_b[rA + i * 1024 + gsel0];
            aF[i][1] = *(const bf16x8*)&As_b[rA + i * 1024 + gsel1];
        }
#pragma unroll
        for (int j = 0; j < 2; j++) {
            bF[j][0] = *(const bf16x8*)&Bs_b[rB + j * 1024 + gsel0];
            bF[j][1] = *(const bf16x8*)&Bs_b[rB + j * 1024 + gsel1];
        }
        if (st1) {
            int ko = (kt + 1) << 6;
#pragma unroll
            for (int c = 0; c < 4; c++) GLD_LDS16(gB[c] + ko, &sB[nbuf][ldoff[c]]);
        }
        BAR;
        __builtin_amdgcn_s_setprio(1);
#pragma unroll
        for (int ks = 0; ks < 2; ks++)
#pragma unroll
            for (int i = 0; i < 4; i++)
#pragma unroll
                for (int j = 0; j < 2; j++)
                    acc[i][j] = __builtin_amdgcn_mfma_f32_16x16x32_bf16(aF[i][ks], bF[j][ks], acc[i][j], 0, 0, 0);
        __builtin_amdgcn_s_setprio(0);
        DRAIN_LGKM;
        BAR;

#pragma unroll
        for (int j = 2; j < 4; j++) {
            bF[j][0] = *(const bf16x8*)&Bs_b[rB + j * 1024 + gsel0];
            bF[j][1] = *(const bf16x8*)&Bs_b[rB + j * 1024 + gsel1];
        }
        if (st2) {
            int ko = (kt + 2) << 6;
#pragma unroll
            for (int c = 0; c < 4; c++) GLD_LDS16(gA[c] + ko, &sA[cur][ldoff[c]]);
        }
        BAR;
        __builtin_amdgcn_s_setprio(1);
#pragma unroll
        for (int ks = 0; ks < 2; ks++)
#pragma unroll
            for (int i = 0; i < 4; i++)
#pragma unroll
                for (int j = 0; j < 2; j++)
                    acc[i][2 + j] = __builtin_amdgcn_mfma_f32_16x16x32_bf16(aF[i][ks], bF[2 + j][ks], acc[i][2 + j], 0, 0, 0);
        __builtin_amdgcn_s_setprio(0);
        DRAIN_LGKM;
        if (st2) { WAIT_VM(4); } else { WAIT_VM(0); }
        BAR;
    }

#pragma unroll
    for (int i = 0; i < 4; i++)
#pragma unroll
        for (int j = 0; j < 4; j++)
#pragma unroll
            for (int r = 0; r < 4; r++) {
                int row = m0 + wr + i * 16 + q4 * 4 + r;
                int col = n0 + wc + j * 16 + l16;
                outb[((size_t)b * M + row) * (size_t)N + col] = acc[i][j][r] + bias[row];
            }
}

// ---------------- 128^2 GEMM (small 512^3 GEMM), bf16 out ----------------
__global__ __launch_bounds__(256) void gemm_bt(
    const __hip_bfloat16* __restrict__ A, const __hip_bfloat16* __restrict__ Bt,
    size_t strideA, size_t strideB, int M, int N, int K,
    __hip_bfloat16* __restrict__ obf) {
    __shared__ alignas(16) unsigned short As[128 * 64];
    __shared__ alignas(16) unsigned short Bs[128 * 64];

    int b = blockIdx.z;
    int m0 = blockIdx.y * 128, n0 = blockIdx.x * 128;
    const __hip_bfloat16* Ab = A + strideA * (size_t)b;
    const __hip_bfloat16* Bb = Bt + strideB * (size_t)b;

    int t = threadIdx.x;
    int lane = t & 63, wv = t >> 6;
    int l16 = lane & 15, q4 = lane >> 4;
    int wr = (wv >> 1) * 64, wc = (wv & 1) * 64;

    int srow = lane >> 3;
    int swz  = ((lane & 7) ^ srow) * 8;

    const __hip_bfloat16* gA[4];
    const __hip_bfloat16* gB[4];
    unsigned short* lA[4];
    unsigned short* lB[4];
#pragma unroll
    for (int c = 0; c < 4; c++) {
        int r = wv * 32 + c * 8;
        gA[c] = Ab + (size_t)(m0 + r + srow) * K + swz;
        gB[c] = Bb + (size_t)(n0 + r + srow) * K + swz;
        lA[c] = &As[r * 64];
        lB[c] = &Bs[r * 64];
    }

    int gsel0 = ((q4) ^ (l16 & 7)) * 8;
    int gsel1 = gsel0 ^ 32;
    int rA = (wr + l16) * 64;
    int rB = (wc + l16) * 64;

    f32x4 acc[4][4] = {};

    for (int k0 = 0; k0 < K; k0 += 64) {
        __syncthreads();
#pragma unroll
        for (int c = 0; c < 4; c++) {
            GLD_LDS16(gA[c] + k0, lA[c]);
            GLD_LDS16(gB[c] + k0, lB[c]);
        }
        __syncthreads();

        bf16x8 af[4], bfr[4];
#pragma unroll
        for (int i = 0; i < 4; i++) {
            af[i]  = *(const bf16x8*)&As[rA + i * 1024 + gsel0];
            bfr[i] = *(const bf16x8*)&Bs[rB + i * 1024 + gsel0];
        }
#pragma unroll
        for (int i = 0; i < 4; i++)
#pragma unroll
            for (int j = 0; j < 4; j++)
                acc[i][j] = __builtin_amdgcn_mfma_f32_16x16x32_bf16(af[i], bfr[j], acc[i][j], 0, 0, 0);
#pragma unroll
        for (int i = 0; i < 4; i++) {
            af[i]  = *(const bf16x8*)&As[rA + i * 1024 + gsel1];
            bfr[i] = *(const bf16x8*)&Bs[rB + i * 1024 + gsel1];
        }
#pragma unroll
        for (int i = 0; i < 4; i++)
#pragma unroll
            for (int j = 0; j < 4; j++)
                acc[i][j] = __builtin_amdgcn_mfma_f32_16x16x32_bf16(af[i], bfr[j], acc[i][j], 0, 0, 0);
    }

#pragma unroll
    for (int i = 0; i < 4; i++)
#pragma unroll
        for (int j = 0; j < 4; j++)
#pragma unroll
            for (int r = 0; r < 4; r++) {
                int row = m0 + wr + i * 16 + q4 * 4 + r;
                int col = n0 + wc + j * 16 + l16;
                obf[((size_t)b * 512 + row) * (size_t)N + col] = __float2bfloat16(acc[i][j][r]);
            }
}

// ---------------- w2[b][o][h*64+d] = sum_e w_out[o][h*64+e] * ctx[d][e]/S[d] ----------------
__global__ __launch_bounds__(256) void w2_kernel(const float* __restrict__ wout,
                                                 const float* __restrict__ ctx,
                                                 const float* __restrict__ Ssum,
                                                 __hip_bfloat16* __restrict__ w2) {
    int ob = blockIdx.x, h = blockIdx.y, b = blockIdx.z;
    __shared__ float cT[64 * 65];  // [e][d], pre-scaled by 1/S[d]
    __shared__ float wT[64 * 65];  // [e][ol]
    __shared__ float Sinv[64];
    int t = threadIdx.x;
    const float* cg = ctx + ((size_t)b * 8 + h) * 4096;
    if (t < 64) Sinv[t] = 1.0f / Ssum[((size_t)b * 8 + h) * 64 + t];
    __syncthreads();
    for (int i = t; i < 4096; i += 256) {
        int d = i >> 6, e = i & 63;
        cT[e * 65 + d] = cg[i] * Sinv[d];
        wT[e * 65 + d] = wout[(size_t)(ob * 64 + d) * 512 + h * 64 + e];
    }
    __syncthreads();
    int ol = t >> 2;
    int db = (t & 3) * 16;
    unsigned short* w2p = (unsigned short*)w2 + ((size_t)b * 512 + ob * 64 + ol) * 512 + h * 64;
    for (int g = 0; g < 4; g++) {
        int d0 = db + g * 4;
        float s0 = 0.f, s1 = 0.f, s2 = 0.f, s3 = 0.f;
#pragma unroll
        for (int e = 0; e < 64; e++) {
            float w = wT[e * 65 + ol];
            s0 += w * cT[e * 65 + d0];
            s1 += w * cT[e * 65 + d0 + 1];
            s2 += w * cT[e * 65 + d0 + 2];
            s3 += w * cT[e * 65 + d0 + 3];
        }
        bf16x4 ov;
        ov[0] = (__bf16)s0; ov[1] = (__bf16)s1; ov[2] = (__bf16)s2; ov[3] = (__bf16)s3;
        *(bf16x4*)(w2p + d0) = ov;
    }
}

// ---------------- launch ----------------
extern "C" void kernel_launch(void* const* d_in, const int* in_sizes, int n_in,
                              void* d_out, int out_size, void* d_ws, size_t ws_size,
                              hipStream_t stream) {
    const float* x     = (const float*)d_in[0];
    const float* w_qkv = (const float*)d_in[1];
    const float* w_out = (const float*)d_in[2];
    const float* b_out = (const float*)d_in[3];
    float* out = (float*)d_out;
    char* ws = (char*)d_ws;

    size_t off_xt  = 0;                                     // bf16 [b][L][C]  32 MiB
    size_t off_wkv = off_xt + (size_t)B_ * L_ * C_ * 2;     // bf16 1024x512    1 MiB
    size_t off_wqT = off_wkv + (size_t)1024 * 512 * 2;      // bf16 512x512   0.5 MiB
    size_t off_ctx = off_wqT + (size_t)512 * 512 * 2;       // fp32 8*8*4096    1 MiB
    size_t off_S   = off_ctx + (size_t)B_ * 8 * 4096 * 4;   // fp32 8*8*64     16 KiB
    size_t off_w2  = off_S + (size_t)B_ * 8 * 64 * 4;       // bf16 8x512x512   4 MiB
    size_t off_w3  = off_w2 + (size_t)B_ * 512 * 512 * 2;   // bf16             4 MiB

    __hip_bfloat16* xt   = (__hip_bfloat16*)(ws + off_xt);
    __hip_bfloat16* wkvb = (__hip_bfloat16*)(ws + off_wkv);
    __hip_bfloat16* wqT  = (__hip_bfloat16*)(ws + off_wqT);
    float*          ctx  = (float*)(ws + off_ctx);
    float*          Sv   = (float*)(ws + off_S);
    __hip_bfloat16* w2   = (__hip_bfloat16*)(ws + off_w2);
    __hip_bfloat16* W3   = (__hip_bfloat16*)(ws + off_w3);

    // prep: transpose x, cvt wkv, build wqT, zero ctx+S (266240 floats = 1040 blocks)
    prep_all<<<5392, 256, 0, stream>>>(x, xt, w_qkv, wkvb, wqT, ctx);

    // fused: k,v = Wkv@x per (n-tile, head, batch); exp+rowsum+P@V^T -> ctx, S
    gemm_kv<<<dim3(L_ / 128, 8, B_), 256, 0, stream>>>(wkvb, xt, ctx, Sv);

    w2_kernel<<<dim3(8, 8, B_), 256, 0, stream>>>(w_out, ctx, Sv, w2);

    // W3[b] = w2[b] @ Wq   (M=512, N=512, K=512)
    gemm_bt<<<dim3(512 / 128, 512 / 128, B_), 256, 0, stream>>>(
        w2, wqT, (size_t)512 * 512, 0, 512, 512, 512, W3);

    // out = W3[b] @ x[b] + b_out   (M=512, N=4096, K=512)
    gemm_p<<<dim3(L_ / 128, 512 / 128, B_), 256, 0, stream>>>(
        W3, xt, (size_t)512 * 512, (size_t)L_ * C_, 512, L_, 512, out, b_out);
}